// Round 8
// baseline (359.277 us; speedup 1.0000x reference)
//
#include <hip/hip_runtime.h>
#include <hip/hip_bf16.h>

typedef __bf16 bf16;
typedef __attribute__((ext_vector_type(8))) __bf16 bf16x8;
typedef __attribute__((ext_vector_type(4))) __bf16 bf16x4;
typedef __attribute__((ext_vector_type(4))) float f32x4;
typedef __attribute__((ext_vector_type(16))) float f32x16;
typedef __attribute__((ext_vector_type(4))) unsigned int u32x4;
typedef __attribute__((ext_vector_type(2))) unsigned int u32x2;

#define DEV static __device__ __forceinline__

DEV f32x4 mfma16(bf16x8 a, bf16x8 b, f32x4 c) {
  return __builtin_amdgcn_mfma_f32_16x16x32_bf16(a, b, c, 0, 0, 0);
}
DEV f32x16 mfma32(bf16x8 a, bf16x8 b, f32x16 c) {
  return __builtin_amdgcn_mfma_f32_32x32x16_bf16(a, b, c, 0, 0, 0);
}
DEV unsigned int pk2(float a, float b) {
  unsigned short ua = __builtin_bit_cast(unsigned short, (bf16)a);
  unsigned short ub = __builtin_bit_cast(unsigned short, (bf16)b);
  return ((unsigned int)ub << 16) | ua;
}
DEV void gload16(const void* g, void* l) {
  __builtin_amdgcn_global_load_lds(
      (const __attribute__((address_space(1))) unsigned int*)g,
      (__attribute__((address_space(3))) unsigned int*)l, 16, 0, 0);
}
// Exchange: ret.x = {a.lanes0-31, b.lanes0-31}; ret.y = {a.lanes32-63, b.lanes32-63}
DEV u32x2 xhalf(unsigned int a, unsigned int b, int hi) {
#if __has_builtin(__builtin_amdgcn_permlane32_swap)
  return __builtin_amdgcn_permlane32_swap(a, b, false, false);
#else
  unsigned int xa = __shfl_xor(a, 32), xb = __shfl_xor(b, 32);
  u32x2 r;
  r.x = hi ? xb : a;
  r.y = hi ? b : xa;
  return r;
#endif
}

// Problem sizes: B=2, S=2048, D=1024, H=16, DK=64, 3D=3072, B*S=4096, B*H=32

// ---------------------------------------------------------------------------
// Kernel 0: fused prep — x f32->bf16 copy; W_qkv and W_o transpose+convert.
// blockIdx.x: [0,2048) xbf, [2048,2816) wqkv^T, [2816,3072) wo^T.
// ---------------------------------------------------------------------------
__global__ __launch_bounds__(256) void prep_k(
    const float* __restrict__ x, bf16* __restrict__ xb,
    const float* __restrict__ wqkv, bf16* __restrict__ wqkvT,
    const float* __restrict__ wo, bf16* __restrict__ woT) {
  __shared__ bf16 ts[64][68];
  const int tid = threadIdx.x;
  const int bid = blockIdx.x;
  if (bid < 2048) {
    int gid = bid * 256 + tid;  // 8 elems each
    const float* src = x + (size_t)gid * 8;
    f32x4 a0 = *(const f32x4*)src;
    f32x4 a1 = *(const f32x4*)(src + 4);
    bf16x8 pk;
#pragma unroll
    for (int j = 0; j < 4; ++j) { pk[j] = (bf16)a0[j]; pk[j + 4] = (bf16)a1[j]; }
    *(bf16x8*)(xb + (size_t)gid * 8) = pk;
    return;
  }
  const float* w;
  bf16* wt;
  int N, K, n0, k0;
  if (bid < 2816) {
    int r = bid - 2048;
    w = wqkv; wt = wqkvT; N = 3072; K = 1024;
    n0 = (r % 48) * 64; k0 = (r / 48) * 64;
  } else {
    int r = bid - 2816;
    w = wo; wt = woT; N = 1024; K = 1024;
    n0 = (r % 16) * 64; k0 = (r / 16) * 64;
  }
  const int tr = tid >> 4;
  const int tc = (tid & 15) * 4;
#pragma unroll
  for (int p = 0; p < 4; ++p) {
    int kr = p * 16 + tr;
    f32x4 v = *(const f32x4*)(w + (size_t)(k0 + kr) * N + n0 + tc);
#pragma unroll
    for (int j = 0; j < 4; ++j) ts[tc + j][kr] = (bf16)v[j];
  }
  __syncthreads();
#pragma unroll
  for (int p = 0; p < 4; ++p) {
    int nr = p * 16 + tr;
    bf16x4 o4;
#pragma unroll
    for (int j = 0; j < 4; ++j) o4[j] = ts[nr][tc + j];
    *(bf16x4*)(wt + (size_t)(n0 + nr) * K + k0 + tc) = o4;
  }
}

// ---------------------------------------------------------------------------
// Kernel 1: qkv = xb @ W_qkvT^T + b_qkv. Both operands bf16 [rows][1024],
// staged via global_load_lds(16B) with pre-swizzled source (XOR (row&7)<<4
// within 128B rows). BK=64, 128x128 tile, 32 MFMA per barrier pair.
// q written PRE-SCALED by log2(e)/8 to [B,H,S,64]; k [B,H,S,64];
// V written TRANSPOSED [B,H,64,S].
// ---------------------------------------------------------------------------
__global__ __launch_bounds__(256, 2) void qkv_gemm_k(
    const bf16* __restrict__ xb, const bf16* __restrict__ wt,
    const float* __restrict__ bias,
    bf16* __restrict__ qo, bf16* __restrict__ ko, bf16* __restrict__ vt) {
  __shared__ __align__(16) char As[16384];  // [128 m][128B = 64 k] swizzled
  __shared__ __align__(16) char Bs[16384];  // [128 n][128B = 64 k] swizzled
  const int tid = threadIdx.x;
  const int lane = tid & 63;
  const int wid = tid >> 6;
  const int wm = wid >> 1, wn = wid & 1;
  const int l16 = lane & 15, lhi = lane >> 4;
  const int m0 = blockIdx.y * 128;
  const int n0 = blockIdx.x * 128;
  const char* ap = (const char*)xb;
  const char* bp = (const char*)wt;

  f32x4 acc[4][4] = {};

  for (int kt = 0; kt < 1024; kt += 64) {
#pragma unroll
    for (int i = 0; i < 4; ++i) {
      int n = i * 256 + wid * 64 + lane;  // chunk 0..1023
      int row = n >> 3, c16 = n & 7;
      gload16(ap + (size_t)(m0 + row) * 2048 + kt * 2 + ((c16 * 16) ^ ((row & 7) << 4)),
              As + (i * 256 + wid * 64) * 16);
    }
#pragma unroll
    for (int i = 0; i < 4; ++i) {
      int n = i * 256 + wid * 64 + lane;
      int row = n >> 3, c16 = n & 7;
      gload16(bp + (size_t)(n0 + row) * 2048 + kt * 2 + ((c16 * 16) ^ ((row & 7) << 4)),
              Bs + (i * 256 + wid * 64) * 16);
    }
    __syncthreads();
#pragma unroll
    for (int kc = 0; kc < 2; ++kc) {
      bf16x8 af[4], bfr[4];
#pragma unroll
      for (int ii = 0; ii < 4; ++ii) {
        int row = wm * 64 + ii * 16 + l16;
        af[ii] = *(const bf16x8*)(As + row * 128 +
                                  ((kc * 64 + lhi * 16) ^ ((row & 7) << 4)));
      }
#pragma unroll
      for (int jj = 0; jj < 4; ++jj) {
        int n = wn * 64 + jj * 16 + l16;
        bfr[jj] = *(const bf16x8*)(Bs + n * 128 +
                                   ((kc * 64 + lhi * 16) ^ ((n & 7) << 4)));
      }
#pragma unroll
      for (int ii = 0; ii < 4; ++ii)
#pragma unroll
        for (int jj = 0; jj < 4; ++jj)
          acc[ii][jj] = mfma16(af[ii], bfr[jj], acc[ii][jj]);
    }
    __syncthreads();
  }

  const float SCQ = 0.18033688011112042f;  // log2(e)/8
#pragma unroll
  for (int jj = 0; jj < 4; ++jj) {
    int nbase = n0 + wn * 64 + jj * 16;  // 16-aligned, within one 64-col q/k/v span
    int h = nbase / 192;
    int rem = nbase - h * 192;
    int type = rem >> 6;
    int dk0 = rem & 63;
    float bv = bias[nbase + l16];
    if (type < 2) {
      bf16* dst = (type == 0) ? qo : ko;
      float scl = (type == 0) ? SCQ : 1.0f;
#pragma unroll
      for (int ii = 0; ii < 4; ++ii) {
#pragma unroll
        for (int r = 0; r < 4; ++r) {
          int mrow = m0 + wm * 64 + ii * 16 + lhi * 4 + r;
          int b = mrow >> 11, s = mrow & 2047;
          dst[(size_t)((b * 16 + h) * 2048 + s) * 64 + dk0 + l16] =
              (bf16)((acc[ii][jj][r] + bv) * scl);
        }
      }
    } else {
      // V^T: vt[((b*16+h)*64 + dk)*2048 + s]
#pragma unroll
      for (int ii = 0; ii < 4; ++ii) {
        int s0 = m0 + wm * 64 + ii * 16 + lhi * 4;
        int b = s0 >> 11, s = s0 & 2047;
        bf16x4 w4;
#pragma unroll
        for (int r = 0; r < 4; ++r) w4[r] = (bf16)(acc[ii][jj][r] + bv);
        *(bf16x4*)(vt + (size_t)((b * 16 + h) * 64 + dk0 + l16) * 2048 + s) = w4;
      }
    }
  }
}

// ---------------------------------------------------------------------------
// Kernel 2: flash attention. 64 q-rows per wave (amortizes K/V LDS reads),
// 4-way kv-split (blockIdx.z) for 4 blocks/CU occupancy. 32x32 swapped-
// operand, fixed-max softmax, 2-phase LDS pipeline. Partials in bf16.
// ---------------------------------------------------------------------------
__global__ __launch_bounds__(256, 4) void attn_k(
    const bf16* __restrict__ q, const bf16* __restrict__ k,
    const bf16* __restrict__ vt, bf16* __restrict__ opart,
    float* __restrict__ lpart) {
  __shared__ __align__(16) char Ks[2][8192];  // [64 kv][128B], swizzled
  __shared__ __align__(16) char Vs[2][8192];  // [64 d][128B], swizzled
  const int tid = threadIdx.x;
  const int lane = tid & 63;
  const int wid = tid >> 6;
  const int l31 = lane & 31;
  const int hi = lane >> 5;
  const int bh = blockIdx.x;
  const int half = blockIdx.z;  // kv split index, 0..3
  const bf16* qp = q + (size_t)bh * 2048 * 64;
  const char* kp = (const char*)(k + (size_t)bh * 2048 * 64);
  const char* vp = (const char*)(vt + (size_t)bh * 64 * 2048);
  const int q0 = blockIdx.y * 256 + wid * 64;
  const int kv0 = half * 512;

  // Q frags (B-operand), 2 q-sets: lane holds Q[q0+qs*32+l31][d=c*16+8hi+f]
  bf16x8 qf0[4], qf1[4];
#pragma unroll
  for (int c = 0; c < 4; ++c) {
    qf0[c] = *(const bf16x8*)(qp + (size_t)(q0 + l31) * 64 + c * 16 + 8 * hi);
    qf1[c] = *(const bf16x8*)(qp + (size_t)(q0 + 32 + l31) * 64 + c * 16 + 8 * hi);
  }

  f32x16 ot00 = {}, ot01 = {}, ot10 = {}, ot11 = {};  // [qs][dchunk]
  float l0 = 0.f, l1 = 0.f;

  auto STAGE = [&](int kt, int bs) {
#pragma unroll
    for (int i = 0; i < 2; ++i) {
      int n = i * 256 + wid * 64 + lane;  // chunk index 0..511
      int row = n >> 3, c16 = n & 7;
      const char* src = kp + (size_t)(kt + row) * 128 + ((c16 * 16) ^ ((row & 7) << 4));
      gload16(src, Ks[bs] + (i * 256 + wid * 64) * 16);
    }
#pragma unroll
    for (int i = 0; i < 2; ++i) {
      int n = i * 256 + wid * 64 + lane;
      int row = n >> 3, c16 = n & 7;
      const char* src = vp + (size_t)row * 4096 + (size_t)kt * 2 +
                        ((c16 * 16) ^ ((row & 7) << 4));
      gload16(src, Vs[bs] + (i * 256 + wid * 64) * 16);
    }
  };

  STAGE(kv0, 0);
  __syncthreads();

  for (int t = 0; t < 8; ++t) {
    int bs = t & 1;
    if (t < 7) STAGE(kv0 + (t + 1) * 64, bs ^ 1);

#pragma unroll
    for (int kb = 0; kb < 2; ++kb) {
      bf16x8 kf[4];
#pragma unroll
      for (int c = 0; c < 4; ++c) {
        int row = kb * 32 + l31;
        kf[c] = *(const bf16x8*)(Ks[bs] + row * 128 +
                                 ((c * 32 + 16 * hi) ^ ((row & 7) << 4)));
      }
      f32x16 st0 = {}, st1 = {};
      __builtin_amdgcn_s_setprio(1);
#pragma unroll
      for (int c = 0; c < 4; ++c) {
        st0 = mfma32(kf[c], qf0[c], st0);
        st1 = mfma32(kf[c], qf1[c], st1);
      }
      __builtin_amdgcn_s_setprio(0);
      // lane holds S^T[kv = kb*32 + (r&3)+8*(r>>2)+4*hi][q = qs*32+l31]
      float p0[16], p1[16];
#pragma unroll
      for (int r = 0; r < 16; ++r) {
        p0[r] = __builtin_amdgcn_exp2f(st0[r]);
        l0 += p0[r];
        p1[r] = __builtin_amdgcn_exp2f(st1[r]);
        l1 += p1[r];
      }

      // PV over 2 kv-groups of 16 within this kb
#pragma unroll
      for (int c2 = 0; c2 < 2; ++c2) {
        const int off = c2 * 8;
        unsigned int a0 = pk2(p0[off + 0], p0[off + 1]);
        unsigned int a1 = pk2(p0[off + 2], p0[off + 3]);
        unsigned int a2 = pk2(p0[off + 4], p0[off + 5]);
        unsigned int a3 = pk2(p0[off + 6], p0[off + 7]);
        u32x2 s02 = xhalf(a0, a2, hi);
        u32x2 s13 = xhalf(a1, a3, hi);
        u32x4 wwa;
        wwa.x = s02.x; wwa.y = s13.x; wwa.z = s02.y; wwa.w = s13.y;
        bf16x8 pb0 = __builtin_bit_cast(bf16x8, wwa);
        unsigned int b0 = pk2(p1[off + 0], p1[off + 1]);
        unsigned int b1 = pk2(p1[off + 2], p1[off + 3]);
        unsigned int b2 = pk2(p1[off + 4], p1[off + 5]);
        unsigned int b3 = pk2(p1[off + 6], p1[off + 7]);
        u32x2 t02 = xhalf(b0, b2, hi);
        u32x2 t13 = xhalf(b1, b3, hi);
        u32x4 wwb;
        wwb.x = t02.x; wwb.y = t13.x; wwb.z = t02.y; wwb.w = t13.y;
        bf16x8 pb1 = __builtin_bit_cast(bf16x8, wwb);

        int col = kb * 64 + c2 * 32 + 16 * hi;  // byte col of kv slice
        int r0 = l31, r1 = 32 + l31;
        bf16x8 vf0 = *(const bf16x8*)(Vs[bs] + r0 * 128 + (col ^ ((r0 & 7) << 4)));
        bf16x8 vf1 = *(const bf16x8*)(Vs[bs] + r1 * 128 + (col ^ ((r1 & 7) << 4)));
        __builtin_amdgcn_s_setprio(1);
        ot00 = mfma32(vf0, pb0, ot00);
        ot01 = mfma32(vf1, pb0, ot01);
        ot10 = mfma32(vf0, pb1, ot10);
        ot11 = mfma32(vf1, pb1, ot11);
        __builtin_amdgcn_s_setprio(0);
      }
    }
    __syncthreads();
  }

  // finalize partials
  float lt0 = l0 + __shfl_xor(l0, 32);
  float lt1 = l1 + __shfl_xor(l1, 32);
  if (hi == 0) {
    lpart[(size_t)(half * 32 + bh) * 2048 + q0 + l31] = lt0;
    lpart[(size_t)(half * 32 + bh) * 2048 + q0 + 32 + l31] = lt1;
  }

  bf16* op0 = opart + ((size_t)(half * 32 + bh) * 2048 + q0 + l31) * 64;
  bf16* op1 = opart + ((size_t)(half * 32 + bh) * 2048 + q0 + 32 + l31) * 64;
#pragma unroll
  for (int g = 0; g < 4; ++g) {
    bf16x4 a4, b4, c4, d4;
#pragma unroll
    for (int j = 0; j < 4; ++j) {
      a4[j] = (bf16)ot00[g * 4 + j];
      b4[j] = (bf16)ot01[g * 4 + j];
      c4[j] = (bf16)ot10[g * 4 + j];
      d4[j] = (bf16)ot11[g * 4 + j];
    }
    *(bf16x4*)(op0 + 8 * g + 4 * hi) = a4;
    *(bf16x4*)(op0 + 32 + 8 * g + 4 * hi) = b4;
    *(bf16x4*)(op1 + 8 * g + 4 * hi) = c4;
    *(bf16x4*)(op1 + 32 + 8 * g + 4 * hi) = d4;
  }
}

// ---------------------------------------------------------------------------
// Kernel 2b: combine 4 kv-split partials -> o bf16 [B*S][1024]
// ---------------------------------------------------------------------------
__global__ __launch_bounds__(256) void comb_k(const bf16* __restrict__ opart,
                                              const float* __restrict__ lpart,
                                              bf16* __restrict__ o) {
  const size_t HS = 32ull * 2048 * 64;  // elems per split
  int gid = blockIdx.x * 256 + threadIdx.x;  // 0 .. 1048575
  int dq = gid & 15;
  int s = (gid >> 4) & 2047;
  int bh = gid >> 15;
  size_t i0 = ((size_t)bh * 2048 + s) * 64 + dq * 4;
  float l = 0.f;
#pragma unroll
  for (int sp = 0; sp < 4; ++sp) l += lpart[(size_t)(sp * 32 + bh) * 2048 + s];
  f32x4 acc = {};
#pragma unroll
  for (int sp = 0; sp < 4; ++sp) {
    bf16x4 v = *(const bf16x4*)(opart + sp * HS + i0);
#pragma unroll
    for (int j = 0; j < 4; ++j) acc[j] += (float)v[j];
  }
  float inv = 1.f / l;
  int b = bh >> 4, h = bh & 15;
  bf16x4 r;
#pragma unroll
  for (int j = 0; j < 4; ++j) r[j] = (bf16)(acc[j] * inv);
  *(bf16x4*)(o + (size_t)(b * 2048 + s) * 1024 + h * 64 + dq * 4) = r;
}

// ---------------------------------------------------------------------------
// Kernel 3: out = o @ W_o + b_o (f32). Same gload_lds BK=64 structure.
// ---------------------------------------------------------------------------
__global__ __launch_bounds__(256, 2) void out_gemm_k(
    const bf16* __restrict__ a, const bf16* __restrict__ wt,
    const float* __restrict__ bias, float* __restrict__ out) {
  __shared__ __align__(16) char As[16384];
  __shared__ __align__(16) char Bs[16384];
  const int tid = threadIdx.x;
  const int lane = tid & 63;
  const int wid = tid >> 6;
  const int wm = wid >> 1, wn = wid & 1;
  const int l16 = lane & 15, lhi = lane >> 4;
  const int m0 = blockIdx.y * 128;
  const int n0 = blockIdx.x * 128;
  const char* ap = (const char*)a;
  const char* bp = (const char*)wt;

  f32x4 acc[4][4] = {};

  for (int kt = 0; kt < 1024; kt += 64) {
#pragma unroll
    for (int i = 0; i < 4; ++i) {
      int n = i * 256 + wid * 64 + lane;
      int row = n >> 3, c16 = n & 7;
      gload16(ap + (size_t)(m0 + row) * 2048 + kt * 2 + ((c16 * 16) ^ ((row & 7) << 4)),
              As + (i * 256 + wid * 64) * 16);
    }
#pragma unroll
    for (int i = 0; i < 4; ++i) {
      int n = i * 256 + wid * 64 + lane;
      int row = n >> 3, c16 = n & 7;
      gload16(bp + (size_t)(n0 + row) * 2048 + kt * 2 + ((c16 * 16) ^ ((row & 7) << 4)),
              Bs + (i * 256 + wid * 64) * 16);
    }
    __syncthreads();
#pragma unroll
    for (int kc = 0; kc < 2; ++kc) {
      bf16x8 af[4], bfr[4];
#pragma unroll
      for (int ii = 0; ii < 4; ++ii) {
        int row = wm * 64 + ii * 16 + l16;
        af[ii] = *(const bf16x8*)(As + row * 128 +
                                  ((kc * 64 + lhi * 16) ^ ((row & 7) << 4)));
      }
#pragma unroll
      for (int jj = 0; jj < 4; ++jj) {
        int n = wn * 64 + jj * 16 + l16;
        bfr[jj] = *(const bf16x8*)(Bs + n * 128 +
                                   ((kc * 64 + lhi * 16) ^ ((n & 7) << 4)));
      }
#pragma unroll
      for (int ii = 0; ii < 4; ++ii)
#pragma unroll
        for (int jj = 0; jj < 4; ++jj)
          acc[ii][jj] = mfma16(af[ii], bfr[jj], acc[ii][jj]);
    }
    __syncthreads();
  }

#pragma unroll
  for (int jj = 0; jj < 4; ++jj) {
    int nbase = n0 + wn * 64 + jj * 16;
    float bv = bias[nbase + l16];
#pragma unroll
    for (int ii = 0; ii < 4; ++ii) {
#pragma unroll
      for (int r = 0; r < 4; ++r) {
        int mrow = m0 + wm * 64 + ii * 16 + lhi * 4 + r;
        out[(size_t)mrow * 1024 + nbase + l16] = acc[ii][jj][r] + bv;
      }
    }
  }
}

// ---------------------------------------------------------------------------
extern "C" void kernel_launch(void* const* d_in, const int* in_sizes, int n_in,
                              void* d_out, int out_size, void* d_ws, size_t ws_size,
                              hipStream_t stream) {
  const float* x = (const float*)d_in[0];
  const float* wqkv = (const float*)d_in[1];
  const float* bqkv = (const float*)d_in[2];
  const float* wo = (const float*)d_in[3];
  const float* bo = (const float*)d_in[4];
  float* out = (float*)d_out;

  // ws layout (all bf16 except lpart):
  bf16* qws = (bf16*)d_ws;                 //  8 MB
  bf16* kws = qws + 4194304;               //  8 MB
  bf16* vtws = kws + 4194304;              //  8 MB
  bf16* ows = vtws + 4194304;              //  8 MB
  bf16* wqkvT = ows + 4194304;             //  6 MB
  bf16* woT = wqkvT + 3145728;             //  2 MB
  bf16* opart = woT + 1048576;             // 32 MB  [4][32][2048][64] bf16
  float* lpart = (float*)(opart + 16777216);  // 1 MB [4][32][2048] f32
  // xbf aliases opart: consumed by qkv_gemm BEFORE attn_k writes opart.
  bf16* xbf = opart;                       //  8 MB [4096][1024] bf16

  prep_k<<<3072, 256, 0, stream>>>(x, xbf, wqkv, wqkvT, wo, woT);
  qkv_gemm_k<<<dim3(24, 32), 256, 0, stream>>>(xbf, wqkvT, bqkv, qws, kws, vtws);
  attn_k<<<dim3(32, 8, 4), 256, 0, stream>>>(qws, kws, vtws, opart, lpart);
  comb_k<<<4096, 256, 0, stream>>>(opart, lpart, ows);
  out_gemm_k<<<dim3(8, 32), 256, 0, stream>>>(ows, woT, bo, out);
}

// Round 9
// 289.025 us; speedup vs baseline: 1.2431x; 1.2431x over previous
//
#include <hip/hip_runtime.h>
#include <hip/hip_bf16.h>

typedef __bf16 bf16;
typedef __attribute__((ext_vector_type(8))) __bf16 bf16x8;
typedef __attribute__((ext_vector_type(4))) __bf16 bf16x4;
typedef __attribute__((ext_vector_type(4))) float f32x4;
typedef __attribute__((ext_vector_type(16))) float f32x16;
typedef __attribute__((ext_vector_type(4))) unsigned int u32x4;
typedef __attribute__((ext_vector_type(2))) unsigned int u32x2;

#define DEV static __device__ __forceinline__

DEV f32x4 mfma16(bf16x8 a, bf16x8 b, f32x4 c) {
  return __builtin_amdgcn_mfma_f32_16x16x32_bf16(a, b, c, 0, 0, 0);
}
DEV f32x16 mfma32(bf16x8 a, bf16x8 b, f32x16 c) {
  return __builtin_amdgcn_mfma_f32_32x32x16_bf16(a, b, c, 0, 0, 0);
}
DEV unsigned int pk2(float a, float b) {
  unsigned short ua = __builtin_bit_cast(unsigned short, (bf16)a);
  unsigned short ub = __builtin_bit_cast(unsigned short, (bf16)b);
  return ((unsigned int)ub << 16) | ua;
}
DEV void gload16(const void* g, void* l) {
  __builtin_amdgcn_global_load_lds(
      (const __attribute__((address_space(1))) unsigned int*)g,
      (__attribute__((address_space(3))) unsigned int*)l, 16, 0, 0);
}
// Exchange: ret.x = {a.lanes0-31, b.lanes0-31}; ret.y = {a.lanes32-63, b.lanes32-63}
DEV u32x2 xhalf(unsigned int a, unsigned int b, int hi) {
#if __has_builtin(__builtin_amdgcn_permlane32_swap)
  return __builtin_amdgcn_permlane32_swap(a, b, false, false);
#else
  unsigned int xa = __shfl_xor(a, 32), xb = __shfl_xor(b, 32);
  u32x2 r;
  r.x = hi ? xb : a;
  r.y = hi ? b : xa;
  return r;
#endif
}

// Problem sizes: B=2, S=2048, D=1024, H=16, DK=64, 3D=3072, B*S=4096, B*H=32

// ---------------------------------------------------------------------------
// Kernel 0: fused prep — x f32->bf16 copy; W_qkv and W_o transpose+convert.
// blockIdx.x: [0,2048) xbf, [2048,2816) wqkv^T, [2816,3072) wo^T.
// ---------------------------------------------------------------------------
__global__ __launch_bounds__(256) void prep_k(
    const float* __restrict__ x, bf16* __restrict__ xb,
    const float* __restrict__ wqkv, bf16* __restrict__ wqkvT,
    const float* __restrict__ wo, bf16* __restrict__ woT) {
  __shared__ bf16 ts[64][68];
  const int tid = threadIdx.x;
  const int bid = blockIdx.x;
  if (bid < 2048) {
    int gid = bid * 256 + tid;  // 8 elems each
    const float* src = x + (size_t)gid * 8;
    f32x4 a0 = *(const f32x4*)src;
    f32x4 a1 = *(const f32x4*)(src + 4);
    bf16x8 pk;
#pragma unroll
    for (int j = 0; j < 4; ++j) { pk[j] = (bf16)a0[j]; pk[j + 4] = (bf16)a1[j]; }
    *(bf16x8*)(xb + (size_t)gid * 8) = pk;
    return;
  }
  const float* w;
  bf16* wt;
  int N, K, n0, k0;
  if (bid < 2816) {
    int r = bid - 2048;
    w = wqkv; wt = wqkvT; N = 3072; K = 1024;
    n0 = (r % 48) * 64; k0 = (r / 48) * 64;
  } else {
    int r = bid - 2816;
    w = wo; wt = woT; N = 1024; K = 1024;
    n0 = (r % 16) * 64; k0 = (r / 16) * 64;
  }
  const int tr = tid >> 4;
  const int tc = (tid & 15) * 4;
#pragma unroll
  for (int p = 0; p < 4; ++p) {
    int kr = p * 16 + tr;
    f32x4 v = *(const f32x4*)(w + (size_t)(k0 + kr) * N + n0 + tc);
#pragma unroll
    for (int j = 0; j < 4; ++j) ts[tc + j][kr] = (bf16)v[j];
  }
  __syncthreads();
#pragma unroll
  for (int p = 0; p < 4; ++p) {
    int nr = p * 16 + tr;
    bf16x4 o4;
#pragma unroll
    for (int j = 0; j < 4; ++j) o4[j] = ts[nr][tc + j];
    *(bf16x4*)(wt + (size_t)(n0 + nr) * K + k0 + tc) = o4;
  }
}

// ---------------------------------------------------------------------------
// Kernel 1: qkv = xb @ W_qkvT^T + b_qkv. Both operands bf16 [rows][1024],
// staged via global_load_lds(16B) with pre-swizzled source (XOR (row&7)<<4
// within 128B rows). BK=64, 128x128 tile, 32 MFMA per barrier pair.
// q written PRE-SCALED by log2(e)/8 to [B,H,S,64]; k [B,H,S,64];
// V written TRANSPOSED [B,H,64,S].
// ---------------------------------------------------------------------------
__global__ __launch_bounds__(256, 2) void qkv_gemm_k(
    const bf16* __restrict__ xb, const bf16* __restrict__ wt,
    const float* __restrict__ bias,
    bf16* __restrict__ qo, bf16* __restrict__ ko, bf16* __restrict__ vt) {
  __shared__ __align__(16) char As[16384];  // [128 m][128B = 64 k] swizzled
  __shared__ __align__(16) char Bs[16384];  // [128 n][128B = 64 k] swizzled
  const int tid = threadIdx.x;
  const int lane = tid & 63;
  const int wid = tid >> 6;
  const int wm = wid >> 1, wn = wid & 1;
  const int l16 = lane & 15, lhi = lane >> 4;
  const int m0 = blockIdx.y * 128;
  const int n0 = blockIdx.x * 128;
  const char* ap = (const char*)xb;
  const char* bp = (const char*)wt;

  f32x4 acc[4][4] = {};

  for (int kt = 0; kt < 1024; kt += 64) {
#pragma unroll
    for (int i = 0; i < 4; ++i) {
      int n = i * 256 + wid * 64 + lane;  // chunk 0..1023
      int row = n >> 3, c16 = n & 7;
      gload16(ap + (size_t)(m0 + row) * 2048 + kt * 2 + ((c16 * 16) ^ ((row & 7) << 4)),
              As + (i * 256 + wid * 64) * 16);
    }
#pragma unroll
    for (int i = 0; i < 4; ++i) {
      int n = i * 256 + wid * 64 + lane;
      int row = n >> 3, c16 = n & 7;
      gload16(bp + (size_t)(n0 + row) * 2048 + kt * 2 + ((c16 * 16) ^ ((row & 7) << 4)),
              Bs + (i * 256 + wid * 64) * 16);
    }
    __syncthreads();
#pragma unroll
    for (int kc = 0; kc < 2; ++kc) {
      bf16x8 af[4], bfr[4];
#pragma unroll
      for (int ii = 0; ii < 4; ++ii) {
        int row = wm * 64 + ii * 16 + l16;
        af[ii] = *(const bf16x8*)(As + row * 128 +
                                  ((kc * 64 + lhi * 16) ^ ((row & 7) << 4)));
      }
#pragma unroll
      for (int jj = 0; jj < 4; ++jj) {
        int n = wn * 64 + jj * 16 + l16;
        bfr[jj] = *(const bf16x8*)(Bs + n * 128 +
                                   ((kc * 64 + lhi * 16) ^ ((n & 7) << 4)));
      }
#pragma unroll
      for (int ii = 0; ii < 4; ++ii)
#pragma unroll
        for (int jj = 0; jj < 4; ++jj)
          acc[ii][jj] = mfma16(af[ii], bfr[jj], acc[ii][jj]);
    }
    __syncthreads();
  }

  const float SCQ = 0.18033688011112042f;  // log2(e)/8
#pragma unroll
  for (int jj = 0; jj < 4; ++jj) {
    int nbase = n0 + wn * 64 + jj * 16;  // 16-aligned, within one 64-col q/k/v span
    int h = nbase / 192;
    int rem = nbase - h * 192;
    int type = rem >> 6;
    int dk0 = rem & 63;
    float bv = bias[nbase + l16];
    if (type < 2) {
      bf16* dst = (type == 0) ? qo : ko;
      float scl = (type == 0) ? SCQ : 1.0f;
#pragma unroll
      for (int ii = 0; ii < 4; ++ii) {
#pragma unroll
        for (int r = 0; r < 4; ++r) {
          int mrow = m0 + wm * 64 + ii * 16 + lhi * 4 + r;
          int b = mrow >> 11, s = mrow & 2047;
          dst[(size_t)((b * 16 + h) * 2048 + s) * 64 + dk0 + l16] =
              (bf16)((acc[ii][jj][r] + bv) * scl);
        }
      }
    } else {
      // V^T: vt[((b*16+h)*64 + dk)*2048 + s]
#pragma unroll
      for (int ii = 0; ii < 4; ++ii) {
        int s0 = m0 + wm * 64 + ii * 16 + lhi * 4;
        int b = s0 >> 11, s = s0 & 2047;
        bf16x4 w4;
#pragma unroll
        for (int r = 0; r < 4; ++r) w4[r] = (bf16)(acc[ii][jj][r] + bv);
        *(bf16x4*)(vt + (size_t)((b * 16 + h) * 64 + dk0 + l16) * 2048 + s) = w4;
      }
    }
  }
}

// ---------------------------------------------------------------------------
// Kernel 2: flash attention. 64 q-rows per wave, 4-way kv-split, 32x32
// swapped-operand, fixed-max softmax, 2-phase LDS pipeline. Partials bf16.
// Epilogue stages O^T through per-wave LDS scratch (K/V buffers are dead
// after the last barrier) -> fully coalesced 16B/lane global stores.
// ---------------------------------------------------------------------------
__global__ __launch_bounds__(256, 4) void attn_k(
    const bf16* __restrict__ q, const bf16* __restrict__ k,
    const bf16* __restrict__ vt, bf16* __restrict__ opart,
    float* __restrict__ lpart) {
  __shared__ __align__(16) char Ks[2][8192];  // [64 kv][128B], swizzled
  __shared__ __align__(16) char Vs[2][8192];  // [64 d][128B], swizzled
  const int tid = threadIdx.x;
  const int lane = tid & 63;
  const int wid = tid >> 6;
  const int l31 = lane & 31;
  const int hi = lane >> 5;
  const int bh = blockIdx.x;
  const int half = blockIdx.z;  // kv split index, 0..3
  const bf16* qp = q + (size_t)bh * 2048 * 64;
  const char* kp = (const char*)(k + (size_t)bh * 2048 * 64);
  const char* vp = (const char*)(vt + (size_t)bh * 64 * 2048);
  const int q0 = blockIdx.y * 256 + wid * 64;
  const int kv0 = half * 512;

  // Q frags (B-operand), 2 q-sets: lane holds Q[q0+qs*32+l31][d=c*16+8hi+f]
  bf16x8 qf0[4], qf1[4];
#pragma unroll
  for (int c = 0; c < 4; ++c) {
    qf0[c] = *(const bf16x8*)(qp + (size_t)(q0 + l31) * 64 + c * 16 + 8 * hi);
    qf1[c] = *(const bf16x8*)(qp + (size_t)(q0 + 32 + l31) * 64 + c * 16 + 8 * hi);
  }

  f32x16 ot00 = {}, ot01 = {}, ot10 = {}, ot11 = {};  // [qs][dchunk]
  float l0 = 0.f, l1 = 0.f;

  auto STAGE = [&](int kt, int bs) {
#pragma unroll
    for (int i = 0; i < 2; ++i) {
      int n = i * 256 + wid * 64 + lane;  // chunk index 0..511
      int row = n >> 3, c16 = n & 7;
      const char* src = kp + (size_t)(kt + row) * 128 + ((c16 * 16) ^ ((row & 7) << 4));
      gload16(src, Ks[bs] + (i * 256 + wid * 64) * 16);
    }
#pragma unroll
    for (int i = 0; i < 2; ++i) {
      int n = i * 256 + wid * 64 + lane;
      int row = n >> 3, c16 = n & 7;
      const char* src = vp + (size_t)row * 4096 + (size_t)kt * 2 +
                        ((c16 * 16) ^ ((row & 7) << 4));
      gload16(src, Vs[bs] + (i * 256 + wid * 64) * 16);
    }
  };

  STAGE(kv0, 0);
  __syncthreads();

  for (int t = 0; t < 8; ++t) {
    int bs = t & 1;
    if (t < 7) STAGE(kv0 + (t + 1) * 64, bs ^ 1);

#pragma unroll
    for (int kb = 0; kb < 2; ++kb) {
      bf16x8 kf[4];
#pragma unroll
      for (int c = 0; c < 4; ++c) {
        int row = kb * 32 + l31;
        kf[c] = *(const bf16x8*)(Ks[bs] + row * 128 +
                                 ((c * 32 + 16 * hi) ^ ((row & 7) << 4)));
      }
      f32x16 st0 = {}, st1 = {};
      __builtin_amdgcn_s_setprio(1);
#pragma unroll
      for (int c = 0; c < 4; ++c) {
        st0 = mfma32(kf[c], qf0[c], st0);
        st1 = mfma32(kf[c], qf1[c], st1);
      }
      __builtin_amdgcn_s_setprio(0);
      // lane holds S^T[kv = kb*32 + (r&3)+8*(r>>2)+4*hi][q = qs*32+l31]
      float p0[16], p1[16];
#pragma unroll
      for (int r = 0; r < 16; ++r) {
        p0[r] = __builtin_amdgcn_exp2f(st0[r]);
        l0 += p0[r];
        p1[r] = __builtin_amdgcn_exp2f(st1[r]);
        l1 += p1[r];
      }

      // PV over 2 kv-groups of 16 within this kb
#pragma unroll
      for (int c2 = 0; c2 < 2; ++c2) {
        const int off = c2 * 8;
        unsigned int a0 = pk2(p0[off + 0], p0[off + 1]);
        unsigned int a1 = pk2(p0[off + 2], p0[off + 3]);
        unsigned int a2 = pk2(p0[off + 4], p0[off + 5]);
        unsigned int a3 = pk2(p0[off + 6], p0[off + 7]);
        u32x2 s02 = xhalf(a0, a2, hi);
        u32x2 s13 = xhalf(a1, a3, hi);
        u32x4 wwa;
        wwa.x = s02.x; wwa.y = s13.x; wwa.z = s02.y; wwa.w = s13.y;
        bf16x8 pb0 = __builtin_bit_cast(bf16x8, wwa);
        unsigned int b0 = pk2(p1[off + 0], p1[off + 1]);
        unsigned int b1 = pk2(p1[off + 2], p1[off + 3]);
        unsigned int b2 = pk2(p1[off + 4], p1[off + 5]);
        unsigned int b3 = pk2(p1[off + 6], p1[off + 7]);
        u32x2 t02 = xhalf(b0, b2, hi);
        u32x2 t13 = xhalf(b1, b3, hi);
        u32x4 wwb;
        wwb.x = t02.x; wwb.y = t13.x; wwb.z = t02.y; wwb.w = t13.y;
        bf16x8 pb1 = __builtin_bit_cast(bf16x8, wwb);

        int col = kb * 64 + c2 * 32 + 16 * hi;  // byte col of kv slice
        int r0 = l31, r1 = 32 + l31;
        bf16x8 vf0 = *(const bf16x8*)(Vs[bs] + r0 * 128 + (col ^ ((r0 & 7) << 4)));
        bf16x8 vf1 = *(const bf16x8*)(Vs[bs] + r1 * 128 + (col ^ ((r1 & 7) << 4)));
        __builtin_amdgcn_s_setprio(1);
        ot00 = mfma32(vf0, pb0, ot00);
        ot01 = mfma32(vf1, pb0, ot01);
        ot10 = mfma32(vf0, pb1, ot10);
        ot11 = mfma32(vf1, pb1, ot11);
        __builtin_amdgcn_s_setprio(0);
      }
    }
    __syncthreads();
  }

  // l partial sums
  float lt0 = l0 + __shfl_xor(l0, 32);
  float lt1 = l1 + __shfl_xor(l1, 32);
  if (hi == 0) {
    lpart[(size_t)(half * 32 + bh) * 2048 + q0 + l31] = lt0;
    lpart[(size_t)(half * 32 + bh) * 2048 + q0 + 32 + l31] = lt1;
  }

  // ---- coalesced epilogue: per-wave LDS scratch (K/V buffers are dead) ----
  char* scr = (wid < 2) ? Ks[wid] : Vs[wid - 2];  // 8KB: [64 q][128B], swizzled
#pragma unroll
  for (int g = 0; g < 4; ++g) {
    bf16x4 v00, v01, v10, v11;
#pragma unroll
    for (int j = 0; j < 4; ++j) {
      v00[j] = (bf16)ot00[g * 4 + j];
      v01[j] = (bf16)ot01[g * 4 + j];
      v10[j] = (bf16)ot10[g * 4 + j];
      v11[j] = (bf16)ot11[g * 4 + j];
    }
    int r0 = l31, r1 = 32 + l31;
    int sw = (l31 & 7) << 4;  // r0&7 == r1&7
    *(bf16x4*)(scr + r0 * 128 + ((g * 16) ^ sw) + 8 * hi) = v00;
    *(bf16x4*)(scr + r0 * 128 + (((4 + g) * 16) ^ sw) + 8 * hi) = v01;
    *(bf16x4*)(scr + r1 * 128 + ((g * 16) ^ sw) + 8 * hi) = v10;
    *(bf16x4*)(scr + r1 * 128 + (((4 + g) * 16) ^ sw) + 8 * hi) = v11;
  }
  char* obase = (char*)(opart + ((size_t)(half * 32 + bh) * 2048 + q0) * 64);
#pragma unroll
  for (int p = 0; p < 8; ++p) {
    int row = p * 8 + (lane >> 3);
    int gran = lane & 7;
    u32x4 v = *(const u32x4*)(scr + row * 128 + ((gran * 16) ^ ((row & 7) << 4)));
    *(u32x4*)(obase + row * 128 + gran * 16) = v;
  }
}

// ---------------------------------------------------------------------------
// Kernel 2b: combine 4 kv-split partials -> o bf16 [B*S][1024]
// ---------------------------------------------------------------------------
__global__ __launch_bounds__(256) void comb_k(const bf16* __restrict__ opart,
                                              const float* __restrict__ lpart,
                                              bf16* __restrict__ o) {
  const size_t HS = 32ull * 2048 * 64;  // elems per split
  int gid = blockIdx.x * 256 + threadIdx.x;  // 0 .. 1048575
  int dq = gid & 15;
  int s = (gid >> 4) & 2047;
  int bh = gid >> 15;
  size_t i0 = ((size_t)bh * 2048 + s) * 64 + dq * 4;
  float l = 0.f;
#pragma unroll
  for (int sp = 0; sp < 4; ++sp) l += lpart[(size_t)(sp * 32 + bh) * 2048 + s];
  f32x4 acc = {};
#pragma unroll
  for (int sp = 0; sp < 4; ++sp) {
    bf16x4 v = *(const bf16x4*)(opart + sp * HS + i0);
#pragma unroll
    for (int j = 0; j < 4; ++j) acc[j] += (float)v[j];
  }
  float inv = 1.f / l;
  int b = bh >> 4, h = bh & 15;
  bf16x4 r;
#pragma unroll
  for (int j = 0; j < 4; ++j) r[j] = (bf16)(acc[j] * inv);
  *(bf16x4*)(o + (size_t)(b * 2048 + s) * 1024 + h * 64 + dq * 4) = r;
}

// ---------------------------------------------------------------------------
// Kernel 3: out = o @ W_o + b_o (f32). Same gload_lds BK=64 structure.
// ---------------------------------------------------------------------------
__global__ __launch_bounds__(256, 2) void out_gemm_k(
    const bf16* __restrict__ a, const bf16* __restrict__ wt,
    const float* __restrict__ bias, float* __restrict__ out) {
  __shared__ __align__(16) char As[16384];
  __shared__ __align__(16) char Bs[16384];
  const int tid = threadIdx.x;
  const int lane = tid & 63;
  const int wid = tid >> 6;
  const int wm = wid >> 1, wn = wid & 1;
  const int l16 = lane & 15, lhi = lane >> 4;
  const int m0 = blockIdx.y * 128;
  const int n0 = blockIdx.x * 128;
  const char* ap = (const char*)a;
  const char* bp = (const char*)wt;

  f32x4 acc[4][4] = {};

  for (int kt = 0; kt < 1024; kt += 64) {
#pragma unroll
    for (int i = 0; i < 4; ++i) {
      int n = i * 256 + wid * 64 + lane;
      int row = n >> 3, c16 = n & 7;
      gload16(ap + (size_t)(m0 + row) * 2048 + kt * 2 + ((c16 * 16) ^ ((row & 7) << 4)),
              As + (i * 256 + wid * 64) * 16);
    }
#pragma unroll
    for (int i = 0; i < 4; ++i) {
      int n = i * 256 + wid * 64 + lane;
      int row = n >> 3, c16 = n & 7;
      gload16(bp + (size_t)(n0 + row) * 2048 + kt * 2 + ((c16 * 16) ^ ((row & 7) << 4)),
              Bs + (i * 256 + wid * 64) * 16);
    }
    __syncthreads();
#pragma unroll
    for (int kc = 0; kc < 2; ++kc) {
      bf16x8 af[4], bfr[4];
#pragma unroll
      for (int ii = 0; ii < 4; ++ii) {
        int row = wm * 64 + ii * 16 + l16;
        af[ii] = *(const bf16x8*)(As + row * 128 +
                                  ((kc * 64 + lhi * 16) ^ ((row & 7) << 4)));
      }
#pragma unroll
      for (int jj = 0; jj < 4; ++jj) {
        int n = wn * 64 + jj * 16 + l16;
        bfr[jj] = *(const bf16x8*)(Bs + n * 128 +
                                   ((kc * 64 + lhi * 16) ^ ((n & 7) << 4)));
      }
#pragma unroll
      for (int ii = 0; ii < 4; ++ii)
#pragma unroll
        for (int jj = 0; jj < 4; ++jj)
          acc[ii][jj] = mfma16(af[ii], bfr[jj], acc[ii][jj]);
    }
    __syncthreads();
  }

#pragma unroll
  for (int jj = 0; jj < 4; ++jj) {
    int nbase = n0 + wn * 64 + jj * 16;
    float bv = bias[nbase + l16];
#pragma unroll
    for (int ii = 0; ii < 4; ++ii) {
#pragma unroll
      for (int r = 0; r < 4; ++r) {
        int mrow = m0 + wm * 64 + ii * 16 + lhi * 4 + r;
        out[(size_t)mrow * 1024 + nbase + l16] = acc[ii][jj][r] + bv;
      }
    }
  }
}

// ---------------------------------------------------------------------------
extern "C" void kernel_launch(void* const* d_in, const int* in_sizes, int n_in,
                              void* d_out, int out_size, void* d_ws, size_t ws_size,
                              hipStream_t stream) {
  const float* x = (const float*)d_in[0];
  const float* wqkv = (const float*)d_in[1];
  const float* bqkv = (const float*)d_in[2];
  const float* wo = (const float*)d_in[3];
  const float* bo = (const float*)d_in[4];
  float* out = (float*)d_out;

  // ws layout (all bf16 except lpart):
  bf16* qws = (bf16*)d_ws;                 //  8 MB
  bf16* kws = qws + 4194304;               //  8 MB
  bf16* vtws = kws + 4194304;              //  8 MB
  bf16* ows = vtws + 4194304;              //  8 MB
  bf16* wqkvT = ows + 4194304;             //  6 MB
  bf16* woT = wqkvT + 3145728;             //  2 MB
  bf16* opart = woT + 1048576;             // 32 MB  [4][32][2048][64] bf16
  float* lpart = (float*)(opart + 16777216);  // 1 MB [4][32][2048] f32
  // xbf aliases opart: consumed by qkv_gemm BEFORE attn_k writes opart.
  bf16* xbf = opart;                       //  8 MB [4096][1024] bf16

  prep_k<<<3072, 256, 0, stream>>>(x, xbf, wqkv, wqkvT, wo, woT);
  qkv_gemm_k<<<dim3(24, 32), 256, 0, stream>>>(xbf, wqkvT, bqkv, qws, kws, vtws);
  attn_k<<<dim3(32, 8, 4), 256, 0, stream>>>(qws, kws, vtws, opart, lpart);
  comb_k<<<4096, 256, 0, stream>>>(opart, lpart, ows);
  out_gemm_k<<<dim3(8, 32), 256, 0, stream>>>(ows, woT, bo, out);
}

// Round 10
// 123.145 us; speedup vs baseline: 2.9175x; 2.3470x over previous
//
#include <hip/hip_runtime.h>
#include <hip/hip_bf16.h>

typedef __bf16 bf16;
typedef __attribute__((ext_vector_type(8))) __bf16 bf16x8;
typedef __attribute__((ext_vector_type(4))) __bf16 bf16x4;
typedef __attribute__((ext_vector_type(4))) float f32x4;
typedef __attribute__((ext_vector_type(16))) float f32x16;
typedef __attribute__((ext_vector_type(4))) unsigned int u32x4;
typedef __attribute__((ext_vector_type(2))) unsigned int u32x2;

#define DEV static __device__ __forceinline__

DEV f32x4 mfma16(bf16x8 a, bf16x8 b, f32x4 c) {
  return __builtin_amdgcn_mfma_f32_16x16x32_bf16(a, b, c, 0, 0, 0);
}
DEV f32x16 mfma32(bf16x8 a, bf16x8 b, f32x16 c) {
  return __builtin_amdgcn_mfma_f32_32x32x16_bf16(a, b, c, 0, 0, 0);
}
DEV unsigned int pk2(float a, float b) {
  unsigned short ua = __builtin_bit_cast(unsigned short, (bf16)a);
  unsigned short ub = __builtin_bit_cast(unsigned short, (bf16)b);
  return ((unsigned int)ub << 16) | ua;
}
DEV void gload16(const void* g, void* l) {
  __builtin_amdgcn_global_load_lds(
      (const __attribute__((address_space(1))) unsigned int*)g,
      (__attribute__((address_space(3))) unsigned int*)l, 16, 0, 0);
}
// Exchange: ret.x = {a.lanes0-31, b.lanes0-31}; ret.y = {a.lanes32-63, b.lanes32-63}
DEV u32x2 xhalf(unsigned int a, unsigned int b, int hi) {
#if __has_builtin(__builtin_amdgcn_permlane32_swap)
  return __builtin_amdgcn_permlane32_swap(a, b, false, false);
#else
  unsigned int xa = __shfl_xor(a, 32), xb = __shfl_xor(b, 32);
  u32x2 r;
  r.x = hi ? xb : a;
  r.y = hi ? b : xa;
  return r;
#endif
}

// Problem sizes: B=2, S=2048, D=1024, H=16, DK=64, 3D=3072, B*S=4096, B*H=32

// ---------------------------------------------------------------------------
// Kernel 0: fused prep — x f32->bf16 copy; W_qkv and W_o transpose+convert.
// blockIdx.x: [0,2048) xbf, [2048,2816) wqkv^T, [2816,3072) wo^T.
// ---------------------------------------------------------------------------
__global__ __launch_bounds__(256) void prep_k(
    const float* __restrict__ x, bf16* __restrict__ xb,
    const float* __restrict__ wqkv, bf16* __restrict__ wqkvT,
    const float* __restrict__ wo, bf16* __restrict__ woT) {
  __shared__ bf16 ts[64][68];
  const int tid = threadIdx.x;
  const int bid = blockIdx.x;
  if (bid < 2048) {
    int gid = bid * 256 + tid;  // 8 elems each
    const float* src = x + (size_t)gid * 8;
    f32x4 a0 = *(const f32x4*)src;
    f32x4 a1 = *(const f32x4*)(src + 4);
    bf16x8 pk;
#pragma unroll
    for (int j = 0; j < 4; ++j) { pk[j] = (bf16)a0[j]; pk[j + 4] = (bf16)a1[j]; }
    *(bf16x8*)(xb + (size_t)gid * 8) = pk;
    return;
  }
  const float* w;
  bf16* wt;
  int N, K, n0, k0;
  if (bid < 2816) {
    int r = bid - 2048;
    w = wqkv; wt = wqkvT; N = 3072; K = 1024;
    n0 = (r % 48) * 64; k0 = (r / 48) * 64;
  } else {
    int r = bid - 2816;
    w = wo; wt = woT; N = 1024; K = 1024;
    n0 = (r % 16) * 64; k0 = (r / 16) * 64;
  }
  const int tr = tid >> 4;
  const int tc = (tid & 15) * 4;
#pragma unroll
  for (int p = 0; p < 4; ++p) {
    int kr = p * 16 + tr;
    f32x4 v = *(const f32x4*)(w + (size_t)(k0 + kr) * N + n0 + tc);
#pragma unroll
    for (int j = 0; j < 4; ++j) ts[tc + j][kr] = (bf16)v[j];
  }
  __syncthreads();
#pragma unroll
  for (int p = 0; p < 4; ++p) {
    int nr = p * 16 + tr;
    bf16x4 o4;
#pragma unroll
    for (int j = 0; j < 4; ++j) o4[j] = ts[nr][tc + j];
    *(bf16x4*)(wt + (size_t)(n0 + nr) * K + k0 + tc) = o4;
  }
}

// ---------------------------------------------------------------------------
// Kernel 1: qkv = xb @ W_qkvT^T + b_qkv. Both operands bf16 [rows][1024],
// staged via global_load_lds(16B) with pre-swizzled source (XOR (row&7)<<4
// within 128B rows). BK=64, 128x128 tile, 32 MFMA per barrier pair.
// q written PRE-SCALED by log2(e)/8 to [B,H,S,64]; k [B,H,S,64];
// V written TRANSPOSED [B,H,64,S].
// ---------------------------------------------------------------------------
__global__ __launch_bounds__(256, 2) void qkv_gemm_k(
    const bf16* __restrict__ xb, const bf16* __restrict__ wt,
    const float* __restrict__ bias,
    bf16* __restrict__ qo, bf16* __restrict__ ko, bf16* __restrict__ vt) {
  __shared__ __align__(16) char As[16384];  // [128 m][128B = 64 k] swizzled
  __shared__ __align__(16) char Bs[16384];  // [128 n][128B = 64 k] swizzled
  const int tid = threadIdx.x;
  const int lane = tid & 63;
  const int wid = tid >> 6;
  const int wm = wid >> 1, wn = wid & 1;
  const int l16 = lane & 15, lhi = lane >> 4;
  const int m0 = blockIdx.y * 128;
  const int n0 = blockIdx.x * 128;
  const char* ap = (const char*)xb;
  const char* bp = (const char*)wt;

  f32x4 acc[4][4] = {};

  for (int kt = 0; kt < 1024; kt += 64) {
#pragma unroll
    for (int i = 0; i < 4; ++i) {
      int n = i * 256 + wid * 64 + lane;  // chunk 0..1023
      int row = n >> 3, c16 = n & 7;
      gload16(ap + (size_t)(m0 + row) * 2048 + kt * 2 + ((c16 * 16) ^ ((row & 7) << 4)),
              As + (i * 256 + wid * 64) * 16);
    }
#pragma unroll
    for (int i = 0; i < 4; ++i) {
      int n = i * 256 + wid * 64 + lane;
      int row = n >> 3, c16 = n & 7;
      gload16(bp + (size_t)(n0 + row) * 2048 + kt * 2 + ((c16 * 16) ^ ((row & 7) << 4)),
              Bs + (i * 256 + wid * 64) * 16);
    }
    __syncthreads();
#pragma unroll
    for (int kc = 0; kc < 2; ++kc) {
      bf16x8 af[4], bfr[4];
#pragma unroll
      for (int ii = 0; ii < 4; ++ii) {
        int row = wm * 64 + ii * 16 + l16;
        af[ii] = *(const bf16x8*)(As + row * 128 +
                                  ((kc * 64 + lhi * 16) ^ ((row & 7) << 4)));
      }
#pragma unroll
      for (int jj = 0; jj < 4; ++jj) {
        int n = wn * 64 + jj * 16 + l16;
        bfr[jj] = *(const bf16x8*)(Bs + n * 128 +
                                   ((kc * 64 + lhi * 16) ^ ((n & 7) << 4)));
      }
#pragma unroll
      for (int ii = 0; ii < 4; ++ii)
#pragma unroll
        for (int jj = 0; jj < 4; ++jj)
          acc[ii][jj] = mfma16(af[ii], bfr[jj], acc[ii][jj]);
    }
    __syncthreads();
  }

  const float SCQ = 0.18033688011112042f;  // log2(e)/8
#pragma unroll
  for (int jj = 0; jj < 4; ++jj) {
    int nbase = n0 + wn * 64 + jj * 16;  // 16-aligned, within one 64-col q/k/v span
    int h = nbase / 192;
    int rem = nbase - h * 192;
    int type = rem >> 6;
    int dk0 = rem & 63;
    float bv = bias[nbase + l16];
    if (type < 2) {
      bf16* dst = (type == 0) ? qo : ko;
      float scl = (type == 0) ? SCQ : 1.0f;
#pragma unroll
      for (int ii = 0; ii < 4; ++ii) {
#pragma unroll
        for (int r = 0; r < 4; ++r) {
          int mrow = m0 + wm * 64 + ii * 16 + lhi * 4 + r;
          int b = mrow >> 11, s = mrow & 2047;
          dst[(size_t)((b * 16 + h) * 2048 + s) * 64 + dk0 + l16] =
              (bf16)((acc[ii][jj][r] + bv) * scl);
        }
      }
    } else {
      // V^T: vt[((b*16+h)*64 + dk)*2048 + s]
#pragma unroll
      for (int ii = 0; ii < 4; ++ii) {
        int s0 = m0 + wm * 64 + ii * 16 + lhi * 4;
        int b = s0 >> 11, s = s0 & 2047;
        bf16x4 w4;
#pragma unroll
        for (int r = 0; r < 4; ++r) w4[r] = (bf16)(acc[ii][jj][r] + bv);
        *(bf16x4*)(vt + (size_t)((b * 16 + h) * 64 + dk0 + l16) * 2048 + s) = w4;
      }
    }
  }
}

// ---------------------------------------------------------------------------
// Kernel 2: flash attention. 32 q-rows/wave (fits 4 waves/EU without spill),
// 4-way kv-split, 32x32 swapped-operand, fixed-max softmax, 2-phase LDS
// pipeline. bf16 partials written via per-wave LDS scratch (coalesced).
// ---------------------------------------------------------------------------
__global__ __launch_bounds__(256, 4) void attn_k(
    const bf16* __restrict__ q, const bf16* __restrict__ k,
    const bf16* __restrict__ vt, bf16* __restrict__ opart,
    float* __restrict__ lpart) {
  __shared__ __align__(16) char Ks[2][8192];  // [64 kv][128B], swizzled
  __shared__ __align__(16) char Vs[2][8192];  // [64 d][128B], swizzled
  const int tid = threadIdx.x;
  const int lane = tid & 63;
  const int wid = tid >> 6;
  const int l31 = lane & 31;
  const int hi = lane >> 5;
  const int bh = blockIdx.x;
  const int half = blockIdx.z;  // kv split index, 0..3
  const bf16* qp = q + (size_t)bh * 2048 * 64;
  const char* kp = (const char*)(k + (size_t)bh * 2048 * 64);
  const char* vp = (const char*)(vt + (size_t)bh * 64 * 2048);
  const int q0 = blockIdx.y * 128 + wid * 32;
  const int kv0 = half * 512;

  // Q frags (B-operand): lane holds Q[q=q0+l31][d = c*16 + 8*hi + f]
  bf16x8 qf[4];
#pragma unroll
  for (int c = 0; c < 4; ++c)
    qf[c] = *(const bf16x8*)(qp + (size_t)(q0 + l31) * 64 + c * 16 + 8 * hi);

  f32x16 ot0 = {}, ot1 = {};  // O^T accum, d-chunks 0/1; col q = l31
  float l_ = 0.f;

  auto STAGE = [&](int kt, int bs) {
#pragma unroll
    for (int i = 0; i < 2; ++i) {
      int n = i * 256 + wid * 64 + lane;  // chunk index 0..511
      int row = n >> 3, c16 = n & 7;
      const char* src = kp + (size_t)(kt + row) * 128 + ((c16 * 16) ^ ((row & 7) << 4));
      gload16(src, Ks[bs] + (i * 256 + wid * 64) * 16);
    }
#pragma unroll
    for (int i = 0; i < 2; ++i) {
      int n = i * 256 + wid * 64 + lane;
      int row = n >> 3, c16 = n & 7;
      const char* src = vp + (size_t)row * 4096 + (size_t)kt * 2 +
                        ((c16 * 16) ^ ((row & 7) << 4));
      gload16(src, Vs[bs] + (i * 256 + wid * 64) * 16);
    }
  };

  STAGE(kv0, 0);
  __syncthreads();

  for (int t = 0; t < 8; ++t) {
    int bs = t & 1;
    if (t < 7) STAGE(kv0 + (t + 1) * 64, bs ^ 1);

    float p[2][16];
#pragma unroll
    for (int kb = 0; kb < 2; ++kb) {
      bf16x8 kf[4];
#pragma unroll
      for (int c = 0; c < 4; ++c) {
        int row = kb * 32 + l31;
        kf[c] = *(const bf16x8*)(Ks[bs] + row * 128 +
                                 ((c * 32 + 16 * hi) ^ ((row & 7) << 4)));
      }
      f32x16 st = {};
      __builtin_amdgcn_s_setprio(1);
#pragma unroll
      for (int c = 0; c < 4; ++c) st = mfma32(kf[c], qf[c], st);
      __builtin_amdgcn_s_setprio(0);
      // lane holds S^T[kv = kb*32 + (r&3)+8*(r>>2)+4*hi][q = l31]
#pragma unroll
      for (int r = 0; r < 16; ++r) {
        p[kb][r] = __builtin_amdgcn_exp2f(st[r]);  // Q pre-scaled by log2(e)/8
        l_ += p[kb][r];
      }
    }

    // PV over 4 kv-groups of 16
#pragma unroll
    for (int ch = 0; ch < 4; ++ch) {
      const int kb = ch >> 1, off = (ch & 1) * 8;
      unsigned int w0 = pk2(p[kb][off + 0], p[kb][off + 1]);
      unsigned int w1 = pk2(p[kb][off + 2], p[kb][off + 3]);
      unsigned int w2 = pk2(p[kb][off + 4], p[kb][off + 5]);
      unsigned int w3 = pk2(p[kb][off + 6], p[kb][off + 7]);
      u32x2 s02 = xhalf(w0, w2, hi);
      u32x2 s13 = xhalf(w1, w3, hi);
      u32x4 ww;
      ww.x = s02.x;
      ww.y = s13.x;
      ww.z = s02.y;
      ww.w = s13.y;
      bf16x8 pb = __builtin_bit_cast(bf16x8, ww);
      int col = ch * 32 + 16 * hi;
      int r0 = l31, r1 = 32 + l31;
      bf16x8 vf0 = *(const bf16x8*)(Vs[bs] + r0 * 128 + (col ^ ((r0 & 7) << 4)));
      bf16x8 vf1 = *(const bf16x8*)(Vs[bs] + r1 * 128 + (col ^ ((r1 & 7) << 4)));
      __builtin_amdgcn_s_setprio(1);
      ot0 = mfma32(vf0, pb, ot0);
      ot1 = mfma32(vf1, pb, ot1);
      __builtin_amdgcn_s_setprio(0);
    }
    __syncthreads();
  }

  // l partial sums
  float lt = l_ + __shfl_xor(l_, 32);
  if (hi == 0) lpart[(size_t)(half * 32 + bh) * 2048 + q0 + l31] = lt;

  // ---- coalesced epilogue: per-wave 4KB LDS scratch (K/V dead now) ----
  char* scr = &Ks[0][0] + wid * 4096;  // [32 q][128B], swizzled
  {
    int sw = (l31 & 7) << 4;
#pragma unroll
    for (int g = 0; g < 4; ++g) {
      bf16x4 v0, v1;
#pragma unroll
      for (int j = 0; j < 4; ++j) {
        v0[j] = (bf16)ot0[g * 4 + j];
        v1[j] = (bf16)ot1[g * 4 + j];
      }
      *(bf16x4*)(scr + l31 * 128 + ((g * 16) ^ sw) + 8 * hi) = v0;
      *(bf16x4*)(scr + l31 * 128 + (((4 + g) * 16) ^ sw) + 8 * hi) = v1;
    }
  }
  char* obase = (char*)(opart + ((size_t)(half * 32 + bh) * 2048 + q0) * 64);
#pragma unroll
  for (int p = 0; p < 4; ++p) {
    int row = p * 8 + (lane >> 3);
    int gran = lane & 7;
    u32x4 v = *(const u32x4*)(scr + row * 128 + ((gran * 16) ^ ((row & 7) << 4)));
    *(u32x4*)(obase + row * 128 + gran * 16) = v;
  }
}

// ---------------------------------------------------------------------------
// Kernel 2b: combine 4 kv-split partials -> o bf16 [B*S][1024]
// ---------------------------------------------------------------------------
__global__ __launch_bounds__(256) void comb_k(const bf16* __restrict__ opart,
                                              const float* __restrict__ lpart,
                                              bf16* __restrict__ o) {
  const size_t HS = 32ull * 2048 * 64;  // elems per split
  int gid = blockIdx.x * 256 + threadIdx.x;  // 0 .. 1048575
  int dq = gid & 15;
  int s = (gid >> 4) & 2047;
  int bh = gid >> 15;
  size_t i0 = ((size_t)bh * 2048 + s) * 64 + dq * 4;
  float l = 0.f;
#pragma unroll
  for (int sp = 0; sp < 4; ++sp) l += lpart[(size_t)(sp * 32 + bh) * 2048 + s];
  f32x4 acc = {};
#pragma unroll
  for (int sp = 0; sp < 4; ++sp) {
    bf16x4 v = *(const bf16x4*)(opart + sp * HS + i0);
#pragma unroll
    for (int j = 0; j < 4; ++j) acc[j] += (float)v[j];
  }
  float inv = 1.f / l;
  int b = bh >> 4, h = bh & 15;
  bf16x4 r;
#pragma unroll
  for (int j = 0; j < 4; ++j) r[j] = (bf16)(acc[j] * inv);
  *(bf16x4*)(o + (size_t)(b * 2048 + s) * 1024 + h * 64 + dq * 4) = r;
}

// ---------------------------------------------------------------------------
// Kernel 3: out = o @ W_o + b_o (f32). Same gload_lds BK=64 structure.
// ---------------------------------------------------------------------------
__global__ __launch_bounds__(256, 2) void out_gemm_k(
    const bf16* __restrict__ a, const bf16* __restrict__ wt,
    const float* __restrict__ bias, float* __restrict__ out) {
  __shared__ __align__(16) char As[16384];
  __shared__ __align__(16) char Bs[16384];
  const int tid = threadIdx.x;
  const int lane = tid & 63;
  const int wid = tid >> 6;
  const int wm = wid >> 1, wn = wid & 1;
  const int l16 = lane & 15, lhi = lane >> 4;
  const int m0 = blockIdx.y * 128;
  const int n0 = blockIdx.x * 128;
  const char* ap = (const char*)a;
  const char* bp = (const char*)wt;

  f32x4 acc[4][4] = {};

  for (int kt = 0; kt < 1024; kt += 64) {
#pragma unroll
    for (int i = 0; i < 4; ++i) {
      int n = i * 256 + wid * 64 + lane;
      int row = n >> 3, c16 = n & 7;
      gload16(ap + (size_t)(m0 + row) * 2048 + kt * 2 + ((c16 * 16) ^ ((row & 7) << 4)),
              As + (i * 256 + wid * 64) * 16);
    }
#pragma unroll
    for (int i = 0; i < 4; ++i) {
      int n = i * 256 + wid * 64 + lane;
      int row = n >> 3, c16 = n & 7;
      gload16(bp + (size_t)(n0 + row) * 2048 + kt * 2 + ((c16 * 16) ^ ((row & 7) << 4)),
              Bs + (i * 256 + wid * 64) * 16);
    }
    __syncthreads();
#pragma unroll
    for (int kc = 0; kc < 2; ++kc) {
      bf16x8 af[4], bfr[4];
#pragma unroll
      for (int ii = 0; ii < 4; ++ii) {
        int row = wm * 64 + ii * 16 + l16;
        af[ii] = *(const bf16x8*)(As + row * 128 +
                                  ((kc * 64 + lhi * 16) ^ ((row & 7) << 4)));
      }
#pragma unroll
      for (int jj = 0; jj < 4; ++jj) {
        int n = wn * 64 + jj * 16 + l16;
        bfr[jj] = *(const bf16x8*)(Bs + n * 128 +
                                   ((kc * 64 + lhi * 16) ^ ((n & 7) << 4)));
      }
#pragma unroll
      for (int ii = 0; ii < 4; ++ii)
#pragma unroll
        for (int jj = 0; jj < 4; ++jj)
          acc[ii][jj] = mfma16(af[ii], bfr[jj], acc[ii][jj]);
    }
    __syncthreads();
  }

#pragma unroll
  for (int jj = 0; jj < 4; ++jj) {
    int nbase = n0 + wn * 64 + jj * 16;
    float bv = bias[nbase + l16];
#pragma unroll
    for (int ii = 0; ii < 4; ++ii) {
#pragma unroll
      for (int r = 0; r < 4; ++r) {
        int mrow = m0 + wm * 64 + ii * 16 + lhi * 4 + r;
        out[(size_t)mrow * 1024 + nbase + l16] = acc[ii][jj][r] + bv;
      }
    }
  }
}

// ---------------------------------------------------------------------------
extern "C" void kernel_launch(void* const* d_in, const int* in_sizes, int n_in,
                              void* d_out, int out_size, void* d_ws, size_t ws_size,
                              hipStream_t stream) {
  const float* x = (const float*)d_in[0];
  const float* wqkv = (const float*)d_in[1];
  const float* bqkv = (const float*)d_in[2];
  const float* wo = (const float*)d_in[3];
  const float* bo = (const float*)d_in[4];
  float* out = (float*)d_out;

  // ws layout (all bf16 except lpart):
  bf16* qws = (bf16*)d_ws;                 //  8 MB
  bf16* kws = qws + 4194304;               //  8 MB
  bf16* vtws = kws + 4194304;              //  8 MB
  bf16* ows = vtws + 4194304;              //  8 MB
  bf16* wqkvT = ows + 4194304;             //  6 MB
  bf16* woT = wqkvT + 3145728;             //  2 MB
  bf16* opart = woT + 1048576;             // 32 MB  [4][32][2048][64] bf16
  float* lpart = (float*)(opart + 16777216);  // 1 MB [4][32][2048] f32
  // xbf aliases opart: consumed by qkv_gemm BEFORE attn_k writes opart.
  bf16* xbf = opart;                       //  8 MB [4096][1024] bf16

  prep_k<<<3072, 256, 0, stream>>>(x, xbf, wqkv, wqkvT, wo, woT);
  qkv_gemm_k<<<dim3(24, 32), 256, 0, stream>>>(xbf, wqkvT, bqkv, qws, kws, vtws);
  attn_k<<<dim3(32, 16, 4), 256, 0, stream>>>(qws, kws, vtws, opart, lpart);
  comb_k<<<4096, 256, 0, stream>>>(opart, lpart, ows);
  out_gemm_k<<<dim3(8, 32), 256, 0, stream>>>(ows, woT, bo, out);
}

// Round 11
// 107.198 us; speedup vs baseline: 3.3515x; 1.1488x over previous
//
#include <hip/hip_runtime.h>
#include <hip/hip_bf16.h>

typedef __bf16 bf16;
typedef __attribute__((ext_vector_type(8))) __bf16 bf16x8;
typedef __attribute__((ext_vector_type(4))) __bf16 bf16x4;
typedef __attribute__((ext_vector_type(4))) float f32x4;
typedef __attribute__((ext_vector_type(16))) float f32x16;
typedef __attribute__((ext_vector_type(4))) unsigned int u32x4;
typedef __attribute__((ext_vector_type(2))) unsigned int u32x2;

#define DEV static __device__ __forceinline__

DEV f32x4 mfma16(bf16x8 a, bf16x8 b, f32x4 c) {
  return __builtin_amdgcn_mfma_f32_16x16x32_bf16(a, b, c, 0, 0, 0);
}
DEV f32x16 mfma32(bf16x8 a, bf16x8 b, f32x16 c) {
  return __builtin_amdgcn_mfma_f32_32x32x16_bf16(a, b, c, 0, 0, 0);
}
DEV unsigned int pk2(float a, float b) {
  unsigned short ua = __builtin_bit_cast(unsigned short, (bf16)a);
  unsigned short ub = __builtin_bit_cast(unsigned short, (bf16)b);
  return ((unsigned int)ub << 16) | ua;
}
DEV void gload16(const void* g, void* l) {
  __builtin_amdgcn_global_load_lds(
      (const __attribute__((address_space(1))) unsigned int*)g,
      (__attribute__((address_space(3))) unsigned int*)l, 16, 0, 0);
}
// Exchange: ret.x = {a.lanes0-31, b.lanes0-31}; ret.y = {a.lanes32-63, b.lanes32-63}
DEV u32x2 xhalf(unsigned int a, unsigned int b, int hi) {
#if __has_builtin(__builtin_amdgcn_permlane32_swap)
  return __builtin_amdgcn_permlane32_swap(a, b, false, false);
#else
  unsigned int xa = __shfl_xor(a, 32), xb = __shfl_xor(b, 32);
  u32x2 r;
  r.x = hi ? xb : a;
  r.y = hi ? b : xa;
  return r;
#endif
}

// Problem sizes: B=2, S=2048, D=1024, H=16, DK=64, 3D=3072, B*S=4096, B*H=32

// ---------------------------------------------------------------------------
// Kernel 0: fused prep — x f32->bf16 copy; W_qkv and W_o transpose+convert.
// blockIdx.x: [0,2048) xbf, [2048,2816) wqkv^T, [2816,3072) wo^T.
// ---------------------------------------------------------------------------
__global__ __launch_bounds__(256) void prep_k(
    const float* __restrict__ x, bf16* __restrict__ xb,
    const float* __restrict__ wqkv, bf16* __restrict__ wqkvT,
    const float* __restrict__ wo, bf16* __restrict__ woT) {
  __shared__ bf16 ts[64][68];
  const int tid = threadIdx.x;
  const int bid = blockIdx.x;
  if (bid < 2048) {
    int gid = bid * 256 + tid;  // 8 elems each
    const float* src = x + (size_t)gid * 8;
    f32x4 a0 = *(const f32x4*)src;
    f32x4 a1 = *(const f32x4*)(src + 4);
    bf16x8 pk;
#pragma unroll
    for (int j = 0; j < 4; ++j) { pk[j] = (bf16)a0[j]; pk[j + 4] = (bf16)a1[j]; }
    *(bf16x8*)(xb + (size_t)gid * 8) = pk;
    return;
  }
  const float* w;
  bf16* wt;
  int N, K, n0, k0;
  if (bid < 2816) {
    int r = bid - 2048;
    w = wqkv; wt = wqkvT; N = 3072; K = 1024;
    n0 = (r % 48) * 64; k0 = (r / 48) * 64;
  } else {
    int r = bid - 2816;
    w = wo; wt = woT; N = 1024; K = 1024;
    n0 = (r % 16) * 64; k0 = (r / 16) * 64;
  }
  const int tr = tid >> 4;
  const int tc = (tid & 15) * 4;
#pragma unroll
  for (int p = 0; p < 4; ++p) {
    int kr = p * 16 + tr;
    f32x4 v = *(const f32x4*)(w + (size_t)(k0 + kr) * N + n0 + tc);
#pragma unroll
    for (int j = 0; j < 4; ++j) ts[tc + j][kr] = (bf16)v[j];
  }
  __syncthreads();
#pragma unroll
  for (int p = 0; p < 4; ++p) {
    int nr = p * 16 + tr;
    bf16x4 o4;
#pragma unroll
    for (int j = 0; j < 4; ++j) o4[j] = ts[nr][tc + j];
    *(bf16x4*)(wt + (size_t)(n0 + nr) * K + k0 + tc) = o4;
  }
}

// ---------------------------------------------------------------------------
// Kernel 1: qkv = xb @ W_qkvT^T + b_qkv. Both operands bf16 [rows][1024],
// staged via global_load_lds(16B) with pre-swizzled source (XOR (row&7)<<4
// within 128B rows). BK=64, 128x128 tile, 32 MFMA per barrier pair.
// q written PRE-SCALED by log2(e)/8 to [B,H,S,64]; k [B,H,S,64];
// V written TRANSPOSED [B,H,64,S].
// ---------------------------------------------------------------------------
__global__ __launch_bounds__(256, 2) void qkv_gemm_k(
    const bf16* __restrict__ xb, const bf16* __restrict__ wt,
    const float* __restrict__ bias,
    bf16* __restrict__ qo, bf16* __restrict__ ko, bf16* __restrict__ vt) {
  __shared__ __align__(16) char As[16384];  // [128 m][128B = 64 k] swizzled
  __shared__ __align__(16) char Bs[16384];  // [128 n][128B = 64 k] swizzled
  const int tid = threadIdx.x;
  const int lane = tid & 63;
  const int wid = tid >> 6;
  const int wm = wid >> 1, wn = wid & 1;
  const int l16 = lane & 15, lhi = lane >> 4;
  const int m0 = blockIdx.y * 128;
  const int n0 = blockIdx.x * 128;
  const char* ap = (const char*)xb;
  const char* bp = (const char*)wt;

  f32x4 acc[4][4] = {};

  for (int kt = 0; kt < 1024; kt += 64) {
#pragma unroll
    for (int i = 0; i < 4; ++i) {
      int n = i * 256 + wid * 64 + lane;  // chunk 0..1023
      int row = n >> 3, c16 = n & 7;
      gload16(ap + (size_t)(m0 + row) * 2048 + kt * 2 + ((c16 * 16) ^ ((row & 7) << 4)),
              As + (i * 256 + wid * 64) * 16);
    }
#pragma unroll
    for (int i = 0; i < 4; ++i) {
      int n = i * 256 + wid * 64 + lane;
      int row = n >> 3, c16 = n & 7;
      gload16(bp + (size_t)(n0 + row) * 2048 + kt * 2 + ((c16 * 16) ^ ((row & 7) << 4)),
              Bs + (i * 256 + wid * 64) * 16);
    }
    __syncthreads();
#pragma unroll
    for (int kc = 0; kc < 2; ++kc) {
      bf16x8 af[4], bfr[4];
#pragma unroll
      for (int ii = 0; ii < 4; ++ii) {
        int row = wm * 64 + ii * 16 + l16;
        af[ii] = *(const bf16x8*)(As + row * 128 +
                                  ((kc * 64 + lhi * 16) ^ ((row & 7) << 4)));
      }
#pragma unroll
      for (int jj = 0; jj < 4; ++jj) {
        int n = wn * 64 + jj * 16 + l16;
        bfr[jj] = *(const bf16x8*)(Bs + n * 128 +
                                   ((kc * 64 + lhi * 16) ^ ((n & 7) << 4)));
      }
#pragma unroll
      for (int ii = 0; ii < 4; ++ii)
#pragma unroll
        for (int jj = 0; jj < 4; ++jj)
          acc[ii][jj] = mfma16(af[ii], bfr[jj], acc[ii][jj]);
    }
    __syncthreads();
  }

  const float SCQ = 0.18033688011112042f;  // log2(e)/8
#pragma unroll
  for (int jj = 0; jj < 4; ++jj) {
    int nbase = n0 + wn * 64 + jj * 16;  // 16-aligned, within one 64-col q/k/v span
    int h = nbase / 192;
    int rem = nbase - h * 192;
    int type = rem >> 6;
    int dk0 = rem & 63;
    float bv = bias[nbase + l16];
    if (type < 2) {
      bf16* dst = (type == 0) ? qo : ko;
      float scl = (type == 0) ? SCQ : 1.0f;
#pragma unroll
      for (int ii = 0; ii < 4; ++ii) {
#pragma unroll
        for (int r = 0; r < 4; ++r) {
          int mrow = m0 + wm * 64 + ii * 16 + lhi * 4 + r;
          int b = mrow >> 11, s = mrow & 2047;
          dst[(size_t)((b * 16 + h) * 2048 + s) * 64 + dk0 + l16] =
              (bf16)((acc[ii][jj][r] + bv) * scl);
        }
      }
    } else {
      // V^T: vt[((b*16+h)*64 + dk)*2048 + s]
#pragma unroll
      for (int ii = 0; ii < 4; ++ii) {
        int s0 = m0 + wm * 64 + ii * 16 + lhi * 4;
        int b = s0 >> 11, s = s0 & 2047;
        bf16x4 w4;
#pragma unroll
        for (int r = 0; r < 4; ++r) w4[r] = (bf16)(acc[ii][jj][r] + bv);
        *(bf16x4*)(vt + (size_t)((b * 16 + h) * 64 + dk0 + l16) * 2048 + s) = w4;
      }
    }
  }
}

// ---------------------------------------------------------------------------
// Kernel 2: flash attention, in-block kv-split. 512 threads / 8 waves:
// waves 0-3 do kv [0,1024), waves 4-7 do kv [1024,2048) for the same 128
// q-rows, each half with its own 32KB double-buffered LDS pipeline.
// End: half-1 dumps f32 accums+l into its dead stage buffers; half-0
// combines (f32), normalizes, and writes final o via swizzled-scratch
// coalesced stores. No partials in global, no combine kernel.
// ---------------------------------------------------------------------------
__global__ __launch_bounds__(512, 4) void attn_k(
    const bf16* __restrict__ q, const bf16* __restrict__ k,
    const bf16* __restrict__ vt, bf16* __restrict__ o) {
  __shared__ __align__(16) char lds[65536];
  const int tid = threadIdx.x;
  const int lane = tid & 63;
  const int wid = tid >> 6;   // 0..7
  const int half = wid >> 2;  // kv half
  const int wv = wid & 3;     // wave within half
  const int l31 = lane & 31;
  const int hi = lane >> 5;
  const int bh = blockIdx.x;
  const int b = bh >> 4, h = bh & 15;
  const bf16* qp = q + (size_t)bh * 2048 * 64;
  const char* kp = (const char*)(k + (size_t)bh * 2048 * 64);
  const char* vp = (const char*)(vt + (size_t)bh * 64 * 2048);
  const int q0 = blockIdx.y * 128 + wv * 32;
  const int kv0 = half * 1024;
  char* myK = lds + half * 32768;          // [2][8192] K stage
  char* myV = lds + half * 32768 + 16384;  // [2][8192] V stage

  // Q frags (B-operand): lane holds Q[q=q0+l31][d = c*16 + 8*hi + f]
  bf16x8 qf[4];
#pragma unroll
  for (int c = 0; c < 4; ++c)
    qf[c] = *(const bf16x8*)(qp + (size_t)(q0 + l31) * 64 + c * 16 + 8 * hi);

  f32x16 ot0 = {}, ot1 = {};  // O^T accum, d-chunks 0/1; col q = l31
  float la = 0.f, lb = 0.f;

  auto STAGE = [&](int kt, int bs) {
#pragma unroll
    for (int i = 0; i < 2; ++i) {
      int n = i * 256 + wv * 64 + lane;  // chunk 0..511 within half
      int row = n >> 3, c16 = n & 7;
      gload16(kp + (size_t)(kt + row) * 128 + ((c16 * 16) ^ ((row & 7) << 4)),
              myK + bs * 8192 + n * 16);
    }
#pragma unroll
    for (int i = 0; i < 2; ++i) {
      int n = i * 256 + wv * 64 + lane;
      int row = n >> 3, c16 = n & 7;
      gload16(vp + (size_t)row * 4096 + (size_t)kt * 2 + ((c16 * 16) ^ ((row & 7) << 4)),
              myV + bs * 8192 + n * 16);
    }
  };

  auto TILE = [&](int bs, int ktn) {
    if (ktn >= 0) STAGE(ktn, bs ^ 1);
    float p[2][16];
#pragma unroll
    for (int kb = 0; kb < 2; ++kb) {
      bf16x8 kf[4];
#pragma unroll
      for (int c = 0; c < 4; ++c) {
        int row = kb * 32 + l31;
        kf[c] = *(const bf16x8*)(myK + bs * 8192 + row * 128 +
                                 ((c * 32 + 16 * hi) ^ ((row & 7) << 4)));
      }
      f32x16 st = {};
      __builtin_amdgcn_s_setprio(1);
#pragma unroll
      for (int c = 0; c < 4; ++c) st = mfma32(kf[c], qf[c], st);
      __builtin_amdgcn_s_setprio(0);
      // lane holds S^T[kv = kb*32 + (r&3)+8*(r>>2)+4*hi][q = l31]
#pragma unroll
      for (int r = 0; r < 16; ++r) {
        p[kb][r] = __builtin_amdgcn_exp2f(st[r]);  // Q pre-scaled by log2(e)/8
        if (r & 1) lb += p[kb][r]; else la += p[kb][r];
      }
    }
    // PV over 4 kv-groups of 16
#pragma unroll
    for (int ch = 0; ch < 4; ++ch) {
      const int kb = ch >> 1, off = (ch & 1) * 8;
      unsigned int w0 = pk2(p[kb][off + 0], p[kb][off + 1]);
      unsigned int w1 = pk2(p[kb][off + 2], p[kb][off + 3]);
      unsigned int w2 = pk2(p[kb][off + 4], p[kb][off + 5]);
      unsigned int w3 = pk2(p[kb][off + 6], p[kb][off + 7]);
      u32x2 s02 = xhalf(w0, w2, hi);
      u32x2 s13 = xhalf(w1, w3, hi);
      u32x4 ww;
      ww.x = s02.x;
      ww.y = s13.x;
      ww.z = s02.y;
      ww.w = s13.y;
      bf16x8 pb = __builtin_bit_cast(bf16x8, ww);
      int col = ch * 32 + 16 * hi;
      int r0 = l31, r1 = 32 + l31;
      bf16x8 vf0 = *(const bf16x8*)(myV + bs * 8192 + r0 * 128 + (col ^ ((r0 & 7) << 4)));
      bf16x8 vf1 = *(const bf16x8*)(myV + bs * 8192 + r1 * 128 + (col ^ ((r1 & 7) << 4)));
      __builtin_amdgcn_s_setprio(1);
      ot0 = mfma32(vf0, pb, ot0);
      ot1 = mfma32(vf1, pb, ot1);
      __builtin_amdgcn_s_setprio(0);
    }
    __syncthreads();
  };

  STAGE(kv0, 0);
  __syncthreads();
  for (int t = 0; t < 16; t += 2) {
    TILE(0, kv0 + (t + 1) * 64);
    TILE(1, t + 2 < 16 ? kv0 + (t + 2) * 64 : -1);
  }

  // ---- in-block combine ----
  float lt = la + lb;
  lt += __shfl_xor(lt, 32);
  char* cbuf = lds + 32768 + wv * 8192;  // half-1 stage area (dead), 8KB/wave
  float* lbuf = (float*)(lds + 16384);   // half-0 V area (dead), 1KB used
  const int swl = (lane & 7) << 4;
  if (half == 1) {
#pragma unroll
    for (int g = 0; g < 4; ++g) {
      f32x4 v0, v1;
#pragma unroll
      for (int j = 0; j < 4; ++j) { v0[j] = ot0[g * 4 + j]; v1[j] = ot1[g * 4 + j]; }
      *(f32x4*)(cbuf + lane * 128 + ((g * 16) ^ swl)) = v0;
      *(f32x4*)(cbuf + lane * 128 + ((64 + g * 16) ^ swl)) = v1;
    }
    lbuf[wv * 64 + lane] = lt;
  }
  __syncthreads();
  if (half == 0) {
    float ltp = lbuf[wv * 64 + lane];
    float inv = 1.f / (lt + ltp);
#pragma unroll
    for (int g = 0; g < 4; ++g) {
      f32x4 a0 = *(const f32x4*)(cbuf + lane * 128 + ((g * 16) ^ swl));
      f32x4 a1 = *(const f32x4*)(cbuf + lane * 128 + ((64 + g * 16) ^ swl));
#pragma unroll
      for (int j = 0; j < 4; ++j) {
        ot0[g * 4 + j] += a0[j];
        ot1[g * 4 + j] += a1[j];
      }
    }
    // transpose through per-wave scratch (half-0 K area, dead), then
    // coalesced 16B/lane stores straight to o [B*S][1024]
    char* scr = lds + wv * 4096;  // [32 q][128B], swizzled
    int sw = (l31 & 7) << 4;
#pragma unroll
    for (int g = 0; g < 4; ++g) {
      bf16x4 v0, v1;
#pragma unroll
      for (int j = 0; j < 4; ++j) {
        v0[j] = (bf16)(ot0[g * 4 + j] * inv);
        v1[j] = (bf16)(ot1[g * 4 + j] * inv);
      }
      *(bf16x4*)(scr + l31 * 128 + ((g * 16) ^ sw) + 8 * hi) = v0;
      *(bf16x4*)(scr + l31 * 128 + (((4 + g) * 16) ^ sw) + 8 * hi) = v1;
    }
#pragma unroll
    for (int p = 0; p < 4; ++p) {
      int row = p * 8 + (lane >> 3);
      int gran = lane & 7;
      u32x4 v = *(const u32x4*)(scr + row * 128 + ((gran * 16) ^ ((row & 7) << 4)));
      *(u32x4*)((char*)o + ((size_t)(b * 2048 + q0 + row) * 1024 + h * 64) * 2 +
                gran * 16) = v;
    }
  }
}

// ---------------------------------------------------------------------------
// Kernel 3: out = o @ W_o + b_o (f32). 128x64 tiles -> 512 blocks (2/CU)
// so one block's staging overlaps the other's compute. Same gload_lds BK=64.
// ---------------------------------------------------------------------------
__global__ __launch_bounds__(256, 2) void out_gemm_k(
    const bf16* __restrict__ a, const bf16* __restrict__ wt,
    const float* __restrict__ bias, float* __restrict__ out) {
  __shared__ __align__(16) char As[16384];  // [128 m][128B]
  __shared__ __align__(16) char Bs[8192];   // [64 n][128B]
  const int tid = threadIdx.x;
  const int lane = tid & 63;
  const int wid = tid >> 6;
  const int wm = wid >> 1, wn = wid & 1;
  const int l16 = lane & 15, lhi = lane >> 4;
  const int m0 = blockIdx.y * 128;
  const int n0 = blockIdx.x * 64;
  const char* ap = (const char*)a;
  const char* bp = (const char*)wt;

  f32x4 acc[4][2] = {};

  for (int kt = 0; kt < 1024; kt += 64) {
#pragma unroll
    for (int i = 0; i < 4; ++i) {
      int n = i * 256 + tid;
      int row = n >> 3, c16 = n & 7;
      gload16(ap + (size_t)(m0 + row) * 2048 + kt * 2 + ((c16 * 16) ^ ((row & 7) << 4)),
              As + n * 16);
    }
#pragma unroll
    for (int i = 0; i < 2; ++i) {
      int n = i * 256 + tid;
      int row = n >> 3, c16 = n & 7;
      gload16(bp + (size_t)(n0 + row) * 2048 + kt * 2 + ((c16 * 16) ^ ((row & 7) << 4)),
              Bs + n * 16);
    }
    __syncthreads();
#pragma unroll
    for (int kc = 0; kc < 2; ++kc) {
      bf16x8 af[4], bfr[2];
#pragma unroll
      for (int ii = 0; ii < 4; ++ii) {
        int row = wm * 64 + ii * 16 + l16;
        af[ii] = *(const bf16x8*)(As + row * 128 +
                                  ((kc * 64 + lhi * 16) ^ ((row & 7) << 4)));
      }
#pragma unroll
      for (int jj = 0; jj < 2; ++jj) {
        int n = wn * 32 + jj * 16 + l16;
        bfr[jj] = *(const bf16x8*)(Bs + n * 128 +
                                   ((kc * 64 + lhi * 16) ^ ((n & 7) << 4)));
      }
#pragma unroll
      for (int ii = 0; ii < 4; ++ii)
#pragma unroll
        for (int jj = 0; jj < 2; ++jj)
          acc[ii][jj] = mfma16(af[ii], bfr[jj], acc[ii][jj]);
    }
    __syncthreads();
  }

#pragma unroll
  for (int jj = 0; jj < 2; ++jj) {
    int nbase = n0 + wn * 32 + jj * 16;
    float bv = bias[nbase + l16];
#pragma unroll
    for (int ii = 0; ii < 4; ++ii) {
#pragma unroll
      for (int r = 0; r < 4; ++r) {
        int mrow = m0 + wm * 64 + ii * 16 + lhi * 4 + r;
        out[(size_t)mrow * 1024 + nbase + l16] = acc[ii][jj][r] + bv;
      }
    }
  }
}

// ---------------------------------------------------------------------------
extern "C" void kernel_launch(void* const* d_in, const int* in_sizes, int n_in,
                              void* d_out, int out_size, void* d_ws, size_t ws_size,
                              hipStream_t stream) {
  const float* x = (const float*)d_in[0];
  const float* wqkv = (const float*)d_in[1];
  const float* bqkv = (const float*)d_in[2];
  const float* wo = (const float*)d_in[3];
  const float* bo = (const float*)d_in[4];
  float* out = (float*)d_out;

  // ws layout (all bf16): 48 MB total
  bf16* qws = (bf16*)d_ws;      //  8 MB [B,H,S,64] (pre-scaled)
  bf16* kws = qws + 4194304;    //  8 MB [B,H,S,64]
  bf16* vtws = kws + 4194304;   //  8 MB [B,H,64,S]
  bf16* ows = vtws + 4194304;   //  8 MB [B*S,1024]
  bf16* wqkvT = ows + 4194304;  //  6 MB [3072][1024]
  bf16* woT = wqkvT + 3145728;  //  2 MB [1024][1024]
  bf16* xbf = woT + 1048576;    //  8 MB [4096][1024]

  prep_k<<<3072, 256, 0, stream>>>(x, xbf, wqkv, wqkvT, wo, woT);
  qkv_gemm_k<<<dim3(24, 32), 256, 0, stream>>>(xbf, wqkvT, bqkv, qws, kws, vtws);
  attn_k<<<dim3(32, 16), 512, 0, stream>>>(qws, kws, vtws, ows);
  out_gemm_k<<<dim3(16, 32), 256, 0, stream>>>(ows, woT, bo, out);
}